// Round 2
// 708.194 us; speedup vs baseline: 1.1167x; 1.1167x over previous
//
#include <hip/hip_runtime.h>

#define EPS 1e-5f
#define ROWS 16384    // floats per h-row (128 w * 128 c)
#define IMG  2097152  // floats per image (128*128*128)
#define N4   16777216 // total float4 count

__device__ __forceinline__ float4 f4add(float4 a, float4 b) {
    return make_float4(a.x + b.x, a.y + b.y, a.z + b.z, a.w + b.w);
}

__device__ __forceinline__ float4 ldrow(const float* xp, int r) {
    if ((unsigned)r < 128u) return *(const float4*)(xp + (long)r * ROWS);
    return make_float4(0.f, 0.f, 0.f, 0.f);
}

// ---------------- Kernel 1: per-channel partial sums, 4 load streams --------
__global__ __launch_bounds__(256) void k_sum_part(const float* __restrict__ x,
                                                  float* __restrict__ part) {
    __shared__ float s[128];
    int t = threadIdx.x;
    if (t < 128) s[t] = 0.f;
    __syncthreads();
    int tid = blockIdx.x * 256 + t;
    int stride = gridDim.x * 256;
    const float4* x4 = (const float4*)x;
    const int Q = N4 / 4;  // 4194304, multiple of 32 -> same channel phase
    float a0 = 0.f, a1 = 0.f, a2 = 0.f, a3 = 0.f;
    for (int i = tid; i < Q; i += stride) {
        float4 v0 = x4[i];
        float4 v1 = x4[i + Q];
        float4 v2 = x4[i + 2 * Q];
        float4 v3 = x4[i + 3 * Q];
        a0 += (v0.x + v1.x) + (v2.x + v3.x);
        a1 += (v0.y + v1.y) + (v2.y + v3.y);
        a2 += (v0.z + v1.z) + (v2.z + v3.z);
        a3 += (v0.w + v1.w) + (v2.w + v3.w);
    }
    int c4 = (tid * 4) & 127;
    atomicAdd(&s[c4 + 0], a0);
    atomicAdd(&s[c4 + 1], a1);
    atomicAdd(&s[c4 + 2], a2);
    atomicAdd(&s[c4 + 3], a3);
    __syncthreads();
    if (t < 128) part[blockIdx.x * 128 + t] = s[t];
}

// ---------------- Kernel 2: partial sums of |x - mean|, 4 load streams ------
__global__ __launch_bounds__(256) void k_abs_part(const float* __restrict__ x,
                                                  const float* __restrict__ meanv,
                                                  float* __restrict__ part) {
    __shared__ float s[128];
    int t = threadIdx.x;
    if (t < 128) s[t] = 0.f;
    __syncthreads();
    int tid = blockIdx.x * 256 + t;
    int stride = gridDim.x * 256;
    int c4 = (tid * 4) & 127;
    float m0 = meanv[c4 + 0], m1 = meanv[c4 + 1];
    float m2 = meanv[c4 + 2], m3 = meanv[c4 + 3];
    const float4* x4 = (const float4*)x;
    const int Q = N4 / 4;
    float a0 = 0.f, a1 = 0.f, a2 = 0.f, a3 = 0.f;
    for (int i = tid; i < Q; i += stride) {
        float4 v0 = x4[i];
        float4 v1 = x4[i + Q];
        float4 v2 = x4[i + 2 * Q];
        float4 v3 = x4[i + 3 * Q];
        a0 += (fabsf(v0.x - m0) + fabsf(v1.x - m0)) + (fabsf(v2.x - m0) + fabsf(v3.x - m0));
        a1 += (fabsf(v0.y - m1) + fabsf(v1.y - m1)) + (fabsf(v2.y - m1) + fabsf(v3.y - m1));
        a2 += (fabsf(v0.z - m2) + fabsf(v1.z - m2)) + (fabsf(v2.z - m2) + fabsf(v3.z - m2));
        a3 += (fabsf(v0.w - m3) + fabsf(v1.w - m3)) + (fabsf(v2.w - m3) + fabsf(v3.w - m3));
    }
    atomicAdd(&s[c4 + 0], a0);
    atomicAdd(&s[c4 + 1], a1);
    atomicAdd(&s[c4 + 2], a2);
    atomicAdd(&s[c4 + 3], a3);
    __syncthreads();
    if (t < 128) part[blockIdx.x * 128 + t] = s[t];
}

// ---------------- final reduce: 1024 thr (8 slices x 128 ch) + LDS tree -----
__global__ __launch_bounds__(1024) void k_reduce(const float* __restrict__ part,
                                                 int nb, float* __restrict__ dst,
                                                 int mode) {
    __shared__ float red[1024];
    int t = threadIdx.x;
    int c = t & 127, sl = t >> 7;
    int per = nb >> 3;
    int b0 = sl * per;
    float a = 0.f;
    for (int b = b0; b < b0 + per; ++b) a += part[b * 128 + c];
    red[t] = a;
    __syncthreads();
    if (t < 128) {
        float m = 0.f;
        #pragma unroll
        for (int k = 0; k < 8; ++k) m += red[k * 128 + t];
        m *= (1.0f / 524288.0f);
        dst[t] = mode ? 1.0f / (m + EPS) : m;
    }
}

// ---------------- Kernel 3: fused, column-sliding-window --------------------
// 512 thr = 128 w x 4 c-quads -> each block owns 16 channels: 4 consecutive
// lanes read 64 contiguous bytes (full fetch granule, no cross-XCD waste).
// One barrier per row: write vx(q) AND vd(q-1) into double-buffered A/B,
// sync once, read both. x ring has depth-1 prefetch (row q+4 issued at iter q,
// consumed at iter q+1) so HBM latency hides behind a full iteration.
__global__ __launch_bounds__(512, 4) void k_fused(
    const float* __restrict__ x,
    const float* __restrict__ meanv, const float* __restrict__ isigv,
    const float* __restrict__ gamma, const float* __restrict__ beta,
    const float* __restrict__ lbw, float* __restrict__ out) {
    __shared__ __align__(16) float A[2][134 * 16];
    __shared__ __align__(16) float B[2][134 * 16];

    const int t = threadIdx.x;
    const int w = t >> 2;                  // 0..127
    const int coff = (t & 3) * 4;          // 0,4,8,12
    const int c0 = (blockIdx.x & 7) * 16;  // 16-channel chunk
    const int h0 = (blockIdx.x >> 3) * 64; // row strip
    const int n = blockIdx.y;

    // zero pad slots {0,1,130,131,132,133} x 16 ch x 4 buffers
    if (t < 384) {
        int buf = t / 96, r = t % 96;
        int slot = r >> 4;
        slot = (slot < 2) ? slot : slot + 128;
        float* p = (buf & 2) ? B[buf & 1] : A[buf & 1];
        p[slot * 16 + (r & 15)] = 0.f;
    }

    const int cc = c0 + coff;
    const float* xp = x + (long)n * IMG + (long)w * 128 + cc;
    float*       op = out + (long)n * IMG + (long)w * 128 + cc;

    const float4 bm = *(const float4*)&meanv[cc];
    const float4 bs = *(const float4*)&isigv[cc];
    const float4 wb = *(const float4*)&lbw[cc];
    const float4 gm = *(const float4*)&gamma[cc];
    const float4 bt = *(const float4*)&beta[cc];

    const int lo_w = max(w - 2, 0), hi_w = min(w + 3, 127);
    const float cw = (float)(hi_w - lo_w + 1);

    // x ring invariant: after the shift at iter q, xrK = row (q-4+K); xr8 is
    // the freshly-issued prefetch of row q+4 (first used next iteration).
    float4 xr0, xr1, xr2, xr3, xr4, xr5, xr6, xr7, xr8;
    xr1 = ldrow(xp, h0 - 6); xr2 = ldrow(xp, h0 - 5); xr3 = ldrow(xp, h0 - 4);
    xr4 = ldrow(xp, h0 - 3); xr5 = ldrow(xp, h0 - 2); xr6 = ldrow(xp, h0 - 1);
    xr7 = ldrow(xp, h0);     xr8 = ldrow(xp, h0 + 1);
    xr0 = make_float4(0.f, 0.f, 0.f, 0.f);

    const float4 z4 = make_float4(0.f, 0.f, 0.f, 0.f);
    float4 dr0 = z4, dr1 = z4, dr2 = z4, dr3 = z4, dr4 = z4, dr5 = z4; // dd(q-5..q)
    float4 er0 = z4, er1 = z4, er2 = z4, er3 = z4;                     // ee(q-3..q)

    for (int q = h0 - 2; q <= h0 + 67; ++q) {
        // shift x ring, issue prefetch of row q+4
        xr0 = xr1; xr1 = xr2; xr2 = xr3; xr3 = xr4;
        xr4 = xr5; xr5 = xr6; xr6 = xr7; xr7 = xr8;
        xr8 = ldrow(xp, q + 4);

        // vx(q) over rows q-2..q+3 ; vd(q-1) over dd rows q-6..q-1
        float4 vx = f4add(f4add(f4add(xr2, xr3), f4add(xr4, xr5)), f4add(xr6, xr7));
        float4 vd = f4add(f4add(f4add(dr0, dr1), f4add(dr2, dr3)), f4add(dr4, dr5));
        float* As = A[q & 1];
        float* Bs = B[q & 1];
        *(float4*)&As[(w + 2) * 16 + coff] = vx;
        *(float4*)&Bs[(w + 2) * 16 + coff] = vd;
        __syncthreads();

        // horizontal 6-sum of vx -> local mean deviation at row q
        const float* Ab = &As[w * 16 + coff];
        float4 ha = *(const float4*)(Ab + 0);
        ha = f4add(ha, *(const float4*)(Ab + 16));
        ha = f4add(ha, *(const float4*)(Ab + 32));
        ha = f4add(ha, *(const float4*)(Ab + 48));
        ha = f4add(ha, *(const float4*)(Ab + 64));
        ha = f4add(ha, *(const float4*)(Ab + 80));

        float4 ee = z4, dd = z4;
        if ((unsigned)q < 128u) {
            int lo_h = max(q - 2, 0), hi_h = min(q + 3, 127);
            float inv = 1.0f / ((float)(hi_h - lo_h + 1) * cw);
            ee.x = xr4.x - ha.x * inv;
            ee.y = xr4.y - ha.y * inv;
            ee.z = xr4.z - ha.z * inv;
            ee.w = xr4.w - ha.w * inv;
            dd.x = fabsf(ee.x); dd.y = fabsf(ee.y);
            dd.z = fabsf(ee.z); dd.w = fabsf(ee.w);
        }

        // output row h = q-4 : horizontal 6-sum of vd -> local MAD
        int h = q - 4;
        if (h >= h0) {  // h <= h0+63 by loop bound
            const float* Bb = &Bs[w * 16 + coff];
            float4 hb = *(const float4*)(Bb + 0);
            hb = f4add(hb, *(const float4*)(Bb + 16));
            hb = f4add(hb, *(const float4*)(Bb + 32));
            hb = f4add(hb, *(const float4*)(Bb + 48));
            hb = f4add(hb, *(const float4*)(Bb + 64));
            hb = f4add(hb, *(const float4*)(Bb + 80));

            int lo_h = max(h - 2, 0), hi_h = min(h + 3, 127);
            float inv = 1.0f / ((float)(hi_h - lo_h + 1) * cw);

            float4 o;
            {
                float mad = hb.x * inv;
                float xl = er0.x / (mad + EPS);
                float xb = (xr0.x - bm.x) * bs.x;
                o.x = (wb.x * xl + (1.0f - wb.x) * xb) * gm.x + bt.x;
            }
            {
                float mad = hb.y * inv;
                float xl = er0.y / (mad + EPS);
                float xb = (xr0.y - bm.y) * bs.y;
                o.y = (wb.y * xl + (1.0f - wb.y) * xb) * gm.y + bt.y;
            }
            {
                float mad = hb.z * inv;
                float xl = er0.z / (mad + EPS);
                float xb = (xr0.z - bm.z) * bs.z;
                o.z = (wb.z * xl + (1.0f - wb.z) * xb) * gm.z + bt.z;
            }
            {
                float mad = hb.w * inv;
                float xl = er0.w / (mad + EPS);
                float xb = (xr0.w - bm.w) * bs.w;
                o.w = (wb.w * xl + (1.0f - wb.w) * xb) * gm.w + bt.w;
            }
            *(float4*)(op + (long)h * ROWS) = o;
        }

        // shift deviation rings (after er0/dr0 consumed)
        er0 = er1; er1 = er2; er2 = er3; er3 = ee;
        dr0 = dr1; dr1 = dr2; dr2 = dr3; dr3 = dr4; dr4 = dr5; dr5 = dd;
    }
}

extern "C" void kernel_launch(void* const* d_in, const int* in_sizes, int n_in,
                              void* d_out, int out_size, void* d_ws, size_t ws_size,
                              hipStream_t stream) {
    const float* x     = (const float*)d_in[0];
    const float* gamma = (const float*)d_in[1];
    const float* beta  = (const float*)d_in[2];
    const float* lbw   = (const float*)d_in[3];
    float* out = (float*)d_out;

    float* part  = (float*)d_ws;        // [1024][128]
    float* meanv = part + 131072;       // [128]
    float* isigv = meanv + 128;         // [128]

    k_sum_part<<<1024, 256, 0, stream>>>(x, part);
    k_reduce<<<1, 1024, 0, stream>>>(part, 1024, meanv, 0);
    k_abs_part<<<1024, 256, 0, stream>>>(x, meanv, part);
    k_reduce<<<1, 1024, 0, stream>>>(part, 1024, isigv, 1);

    dim3 g3(16, 32);  // (8 c-chunks x 2 row-strips, batch)
    k_fused<<<g3, 512, 0, stream>>>(x, meanv, isigv, gamma, beta, lbw, out);
}

// Round 4
// 690.675 us; speedup vs baseline: 1.1450x; 1.0254x over previous
//
#include <hip/hip_runtime.h>

#define EPS  1e-5f
#define ROWS 16384    // floats per h-row (128 w * 128 c)
#define IMG  2097152  // floats per image (128*128*128)
#define INVN (1.0f / 524288.0f)   // 1 / (32*128*128)

__device__ __forceinline__ float4 f4add(float4 a, float4 b) {
    return make_float4(a.x + b.x, a.y + b.y, a.z + b.z, a.w + b.w);
}

__device__ __forceinline__ float4 ldrow(const float* xp, int r) {
    if ((unsigned)r < 128u) return *(const float4*)(xp + (long)r * ROWS);
    return make_float4(0.f, 0.f, 0.f, 0.f);
}

// ---------------- stats pass 1: per-channel sum -> gsum (atomics) -----------
// 512 blocks x 512 thr, block-contiguous 512KB chunks, 4 load streams.
__global__ __launch_bounds__(512) void k_stats1(const float* __restrict__ x,
                                                float* __restrict__ gsum) {
    __shared__ float s[128];
    const int t = threadIdx.x;
    if (t < 128) s[t] = 0.f;
    __syncthreads();
    const float4* x4 = (const float4*)x + (long)blockIdx.x * 32768;
    float a0 = 0.f, a1 = 0.f, a2 = 0.f, a3 = 0.f;
    #pragma unroll
    for (int k = 0; k < 16; ++k) {
        float4 v0 = x4[(k +  0) * 512 + t];
        float4 v1 = x4[(k + 16) * 512 + t];
        float4 v2 = x4[(k + 32) * 512 + t];
        float4 v3 = x4[(k + 48) * 512 + t];
        a0 += (v0.x + v1.x) + (v2.x + v3.x);
        a1 += (v0.y + v1.y) + (v2.y + v3.y);
        a2 += (v0.z + v1.z) + (v2.z + v3.z);
        a3 += (v0.w + v1.w) + (v2.w + v3.w);
    }
    const int c4 = (t * 4) & 127;
    atomicAdd(&s[c4 + 0], a0);
    atomicAdd(&s[c4 + 1], a1);
    atomicAdd(&s[c4 + 2], a2);
    atomicAdd(&s[c4 + 3], a3);
    __syncthreads();
    if (t < 128) atomicAdd(&gsum[t], s[t]);
}

// ---------------- stats pass 2: per-channel sum|x-mean| -> gabs -------------
// Same chunks, REVERSE k-order: tail of pass 1's stream is L3-resident.
__global__ __launch_bounds__(512) void k_stats2(const float* __restrict__ x,
                                                const float* __restrict__ gsum,
                                                float* __restrict__ gabs) {
    __shared__ float s[128];
    const int t = threadIdx.x;
    const int c4 = (t * 4) & 127;
    float m0 = gsum[c4 + 0] * INVN, m1 = gsum[c4 + 1] * INVN;
    float m2 = gsum[c4 + 2] * INVN, m3 = gsum[c4 + 3] * INVN;
    if (t < 128) s[t] = 0.f;
    __syncthreads();
    const float4* x4 = (const float4*)x + (long)blockIdx.x * 32768;
    float a0 = 0.f, a1 = 0.f, a2 = 0.f, a3 = 0.f;
    #pragma unroll
    for (int k = 15; k >= 0; --k) {
        float4 v0 = x4[(k +  0) * 512 + t];
        float4 v1 = x4[(k + 16) * 512 + t];
        float4 v2 = x4[(k + 32) * 512 + t];
        float4 v3 = x4[(k + 48) * 512 + t];
        a0 += (fabsf(v0.x - m0) + fabsf(v1.x - m0)) + (fabsf(v2.x - m0) + fabsf(v3.x - m0));
        a1 += (fabsf(v0.y - m1) + fabsf(v1.y - m1)) + (fabsf(v2.y - m1) + fabsf(v3.y - m1));
        a2 += (fabsf(v0.z - m2) + fabsf(v1.z - m2)) + (fabsf(v2.z - m2) + fabsf(v3.z - m2));
        a3 += (fabsf(v0.w - m3) + fabsf(v1.w - m3)) + (fabsf(v2.w - m3) + fabsf(v3.w - m3));
    }
    atomicAdd(&s[c4 + 0], a0);
    atomicAdd(&s[c4 + 1], a1);
    atomicAdd(&s[c4 + 2], a2);
    atomicAdd(&s[c4 + 3], a3);
    __syncthreads();
    if (t < 128) atomicAdd(&gabs[t], s[t]);
}

// ---------------- Kernel 3: fused, column-sliding-window --------------------
// 512 thr = 128 w x 4 c-quads; 16 channels per block (full 64B granules).
// One barrier per row; double-buffered A/B; prefetch depth 2 (row loaded at
// iter q first consumed at q+2). bm/bs derived in-thread from gsum/gabs.
__global__ __launch_bounds__(512, 4) void k_fused(
    const float* __restrict__ x,
    const float* __restrict__ gsum, const float* __restrict__ gabs,
    const float* __restrict__ gamma, const float* __restrict__ beta,
    const float* __restrict__ lbw, float* __restrict__ out) {
    __shared__ __align__(16) float A[2][134 * 16];
    __shared__ __align__(16) float B[2][134 * 16];

    const int t = threadIdx.x;
    const int w = t >> 2;                  // 0..127
    const int coff = (t & 3) * 4;          // 0,4,8,12
    const int c0 = (blockIdx.x & 7) * 16;  // 16-channel chunk
    const int h0 = (blockIdx.x >> 3) * 64; // row strip
    const int n = blockIdx.y;

    // zero pad slots {0,1,130..133} x 16 ch x 4 buffers
    if (t < 384) {
        int buf = t / 96, r = t % 96;
        int slot = r >> 4;
        slot = (slot < 2) ? slot : slot + 128;
        float* p = (buf & 2) ? B[buf & 1] : A[buf & 1];
        p[slot * 16 + (r & 15)] = 0.f;
    }

    const int cc = c0 + coff;
    const float* xp = x + (long)n * IMG + (long)w * 128 + cc;
    float*       op = out + (long)n * IMG + (long)w * 128 + cc;

    float4 bm, bs;
    bm.x = gsum[cc + 0] * INVN; bm.y = gsum[cc + 1] * INVN;
    bm.z = gsum[cc + 2] * INVN; bm.w = gsum[cc + 3] * INVN;
    bs.x = 1.0f / (gabs[cc + 0] * INVN + EPS);
    bs.y = 1.0f / (gabs[cc + 1] * INVN + EPS);
    bs.z = 1.0f / (gabs[cc + 2] * INVN + EPS);
    bs.w = 1.0f / (gabs[cc + 3] * INVN + EPS);
    const float4 wb = *(const float4*)&lbw[cc];
    const float4 gm = *(const float4*)&gamma[cc];
    const float4 bt = *(const float4*)&beta[cc];

    const int lo_w = max(w - 2, 0), hi_w = min(w + 3, 127);
    const float cw = (float)(hi_w - lo_w + 1);

    // x ring, prefetch depth 2: after the shift at iter q, xrK = row(q-4+K)
    // for K=0..8; xr9 is then loaded with row q+5 (first consumed at q+2).
    float4 xr0, xr1, xr2, xr3, xr4, xr5, xr6, xr7, xr8, xr9;
    xr1 = ldrow(xp, h0 - 6); xr2 = ldrow(xp, h0 - 5); xr3 = ldrow(xp, h0 - 4);
    xr4 = ldrow(xp, h0 - 3); xr5 = ldrow(xp, h0 - 2); xr6 = ldrow(xp, h0 - 1);
    xr7 = ldrow(xp, h0);     xr8 = ldrow(xp, h0 + 1); xr9 = ldrow(xp, h0 + 2);
    xr0 = make_float4(0.f, 0.f, 0.f, 0.f);

    const float4 z4 = make_float4(0.f, 0.f, 0.f, 0.f);
    float4 dr0 = z4, dr1 = z4, dr2 = z4, dr3 = z4, dr4 = z4, dr5 = z4; // dd(q-6..q-1)
    float4 er0 = z4, er1 = z4, er2 = z4, er3 = z4;                     // ee(q-4..q-1)

    for (int q = h0 - 2; q <= h0 + 67; ++q) {
        // shift x ring, issue prefetch of row q+5
        xr0 = xr1; xr1 = xr2; xr2 = xr3; xr3 = xr4; xr4 = xr5;
        xr5 = xr6; xr6 = xr7; xr7 = xr8; xr8 = xr9;
        xr9 = ldrow(xp, q + 5);

        // vx(q) over rows q-2..q+3 ; vd for output row q-4 over dd(q-6..q-1)
        float4 vx = f4add(f4add(f4add(xr2, xr3), f4add(xr4, xr5)), f4add(xr6, xr7));
        float4 vd = f4add(f4add(f4add(dr0, dr1), f4add(dr2, dr3)), f4add(dr4, dr5));
        float* As = A[q & 1];
        float* Bs = B[q & 1];
        *(float4*)&As[(w + 2) * 16 + coff] = vx;
        *(float4*)&Bs[(w + 2) * 16 + coff] = vd;
        __syncthreads();

        // horizontal 6-sum of vx -> local mean at row q
        const float* Ab = &As[w * 16 + coff];
        float4 ha = *(const float4*)(Ab + 0);
        ha = f4add(ha, *(const float4*)(Ab + 16));
        ha = f4add(ha, *(const float4*)(Ab + 32));
        ha = f4add(ha, *(const float4*)(Ab + 48));
        ha = f4add(ha, *(const float4*)(Ab + 64));
        ha = f4add(ha, *(const float4*)(Ab + 80));

        float4 ee = z4, dd = z4;
        if ((unsigned)q < 128u) {
            int lo_h = max(q - 2, 0), hi_h = min(q + 3, 127);
            float inv = 1.0f / ((float)(hi_h - lo_h + 1) * cw);
            ee.x = xr4.x - ha.x * inv;
            ee.y = xr4.y - ha.y * inv;
            ee.z = xr4.z - ha.z * inv;
            ee.w = xr4.w - ha.w * inv;
            dd.x = fabsf(ee.x); dd.y = fabsf(ee.y);
            dd.z = fabsf(ee.z); dd.w = fabsf(ee.w);
        }

        // output row h = q-4 : horizontal 6-sum of vd -> local MAD
        int h = q - 4;
        if (h >= h0) {  // h <= h0+63 by loop bound
            const float* Bb = &Bs[w * 16 + coff];
            float4 hb = *(const float4*)(Bb + 0);
            hb = f4add(hb, *(const float4*)(Bb + 16));
            hb = f4add(hb, *(const float4*)(Bb + 32));
            hb = f4add(hb, *(const float4*)(Bb + 48));
            hb = f4add(hb, *(const float4*)(Bb + 64));
            hb = f4add(hb, *(const float4*)(Bb + 80));

            int lo_h = max(h - 2, 0), hi_h = min(h + 3, 127);
            float inv = 1.0f / ((float)(hi_h - lo_h + 1) * cw);

            float4 o;
            {
                float mad = hb.x * inv;
                float xl = er0.x / (mad + EPS);
                float xb = (xr0.x - bm.x) * bs.x;
                o.x = (wb.x * xl + (1.0f - wb.x) * xb) * gm.x + bt.x;
            }
            {
                float mad = hb.y * inv;
                float xl = er0.y / (mad + EPS);
                float xb = (xr0.y - bm.y) * bs.y;
                o.y = (wb.y * xl + (1.0f - wb.y) * xb) * gm.y + bt.y;
            }
            {
                float mad = hb.z * inv;
                float xl = er0.z / (mad + EPS);
                float xb = (xr0.z - bm.z) * bs.z;
                o.z = (wb.z * xl + (1.0f - wb.z) * xb) * gm.z + bt.z;
            }
            {
                float mad = hb.w * inv;
                float xl = er0.w / (mad + EPS);
                float xb = (xr0.w - bm.w) * bs.w;
                o.w = (wb.w * xl + (1.0f - wb.w) * xb) * gm.w + bt.w;
            }
            *(float4*)(op + (long)h * ROWS) = o;
        }

        // shift deviation rings (after er0/dr0 consumed)
        er0 = er1; er1 = er2; er2 = er3; er3 = ee;
        dr0 = dr1; dr1 = dr2; dr2 = dr3; dr3 = dr4; dr4 = dr5; dr5 = dd;
    }
}

extern "C" void kernel_launch(void* const* d_in, const int* in_sizes, int n_in,
                              void* d_out, int out_size, void* d_ws, size_t ws_size,
                              hipStream_t stream) {
    const float* x     = (const float*)d_in[0];
    const float* gamma = (const float*)d_in[1];
    const float* beta  = (const float*)d_in[2];
    const float* lbw   = (const float*)d_in[3];
    float* out = (float*)d_out;

    float* gsum = (float*)d_ws;        // [128]
    float* gabs = gsum + 128;          // [128]

    hipMemsetAsync(gsum, 0, 256 * sizeof(float), stream);

    k_stats1<<<512, 512, 0, stream>>>(x, gsum);
    k_stats2<<<512, 512, 0, stream>>>(x, gsum, gabs);

    dim3 g3(16, 32);  // (8 c-chunks x 2 row-strips, batch)
    k_fused<<<g3, 512, 0, stream>>>(x, gsum, gabs, gamma, beta, lbw, out);
}